// Round 11
// baseline (80.868 us; speedup 1.0000x reference)
//
#include <hip/hip_runtime.h>
#include <hip/hip_bf16.h>
#include <math.h>

// Leapfrog on SPD(32), eigh-free, inverse-free, barrier-free, LDS-free.
//   U = S·P ; Ut = P·S ; H = U·U (= S·P·S·P)
//   M = 0.02·U - 2e-4·H  (= 2DT·S·pi_half)
//   E = exp(M^T) Taylor-3 ; Yt = S·E ; Y = E^T·S = exp(M)·S
//   Sigma_new = 0.5(Y + Yt) + 1e-8 I   (computed fully in registers)
// ONE chain per wave, 4 matrices sequentially with next-matrix prefetch
// (2-stage pipeline, named A/B buffers — all statically indexed).
// 32x32x16 bf16 MFMA; RNE packs; D-layout -> B-frag via
// v_permlane32_swap_b32 (verified R5/R6: swap32(x,y) exchanges
// x.lanes[32:63] <-> y.lanes[0:31]); B-frag regs reused as A-operands
// (validated R10). Final products in exact hi/lo split bf16.
// phi retraction fused (lane 0, double, floor-based mod-2pi).

typedef unsigned int u32;
typedef __attribute__((ext_vector_type(8))) short bf16x8;
typedef __attribute__((ext_vector_type(16))) float f32x16;

#define ITERS 4

union U4 { u32 u[4]; bf16x8 v; };

__device__ __forceinline__ bf16x8 mk8(u32 a, u32 b, u32 c, u32 d) {
    U4 t; t.u[0] = a; t.u[1] = b; t.u[2] = c; t.u[3] = d; return t.v;
}

// pack bf16(x),bf16(y) with round-nearest-even: low16 = x, high16 = y
__device__ __forceinline__ u32 pk2(float x, float y) {
    float2 f2; f2.x = x; f2.y = y;
    __hip_bfloat162 h2 = __float22bfloat162_rn(f2);
    union { __hip_bfloat162 h; u32 u; } c; c.h = h2; return c.u;
}

__device__ __forceinline__ float asfloat(u32 b) {
    union { u32 u; float f; } c; c.u = b; return c.f;
}

__device__ __forceinline__ f32x16 zero16() {
    f32x16 z;
#pragma unroll
    for (int i = 0; i < 16; ++i) z[i] = 0.f;
    return z;
}

struct Frag8 { u32 r[8]; };

// v_permlane32_swap_b32: x.lanes[32:63] <-> y.lanes[0:31]
__device__ __forceinline__ void swap32(u32& x, u32& y) {
    asm("v_permlane32_swap_b32 %0, %1" : "+v"(x), "+v"(y));
}

// packed-pair regs p[8] (D-layout pairs) -> B-fragment order.
__device__ __forceinline__ void xchg(const u32* p, Frag8& B) {
    { u32 x = p[0], y = p[2]; swap32(x, y); B.r[0] = x; B.r[2] = y; }
    { u32 x = p[1], y = p[3]; swap32(x, y); B.r[1] = x; B.r[3] = y; }
    { u32 x = p[4], y = p[6]; swap32(x, y); B.r[4] = x; B.r[6] = y; }
    { u32 x = p[5], y = p[7]; swap32(x, y); B.r[5] = x; B.r[7] = y; }
}

__device__ __forceinline__ void bconv(const f32x16& X, Frag8& B) {
    u32 p[8];
#pragma unroll
    for (int i = 0; i < 8; ++i) p[i] = pk2(X[2*i], X[2*i+1]);
    xchg(p, B);
}

__device__ __forceinline__ void bconv_s(const f32x16& X, float scale, Frag8& B) {
    u32 p[8];
#pragma unroll
    for (int i = 0; i < 8; ++i) p[i] = pk2(X[2*i] * scale, X[2*i+1] * scale);
    xchg(p, B);
}

// D-layout f32x16 -> exact hi/lo split bf16 B-fragments
__device__ __forceinline__ void bconv_split(const f32x16& X, Frag8& Bh, Frag8& Bl) {
    u32 p[8], q[8];
#pragma unroll
    for (int i = 0; i < 8; ++i) {
        const float x = X[2*i], y = X[2*i+1];
        p[i] = pk2(x, y);
        const float lx = x - asfloat(p[i] << 16);
        const float ly = y - asfloat(p[i] & 0xffff0000u);
        q[i] = pk2(lx, ly);
    }
    xchg(p, Bh);
    xchg(q, Bl);
}

__device__ __forceinline__ f32x16 MFMA1(const u32* a, const u32* b, f32x16 acc) {
    return __builtin_amdgcn_mfma_f32_32x32x16_bf16(
        mk8(a[0], a[1], a[2], a[3]), mk8(b[0], b[1], b[2], b[3]), acc, 0, 0, 0);
}

__device__ __forceinline__ f32x16 matmul(const Frag8& A, const Frag8& B, f32x16 acc) {
    acc = MFMA1(A.r,     B.r,     acc);   // k = 0..15
    acc = MFMA1(A.r + 4, B.r + 4, acc);   // k = 16..31
    return acc;
}

struct InBuf {
    float4 sv[4], pv[4];
    float  ph[3], pq[3];
};

__device__ __forceinline__ void loadm(const float* __restrict__ Sg,
                                      const float* __restrict__ Pg,
                                      const float* __restrict__ phig,
                                      const float* __restrict__ piphig,
                                      int bn, int fr, int h, InBuf& b)
{
    const size_t gbase = (size_t)bn * 1024;
    const float* Srow = Sg + gbase + fr * 32 + h * 8;
    const float* Prow = Pg + gbase + fr * 32 + h * 8;
    b.sv[0] = *(const float4*)(Srow +  0);
    b.sv[1] = *(const float4*)(Srow +  4);
    b.sv[2] = *(const float4*)(Srow + 16);
    b.sv[3] = *(const float4*)(Srow + 20);
    b.pv[0] = *(const float4*)(Prow +  0);
    b.pv[1] = *(const float4*)(Prow +  4);
    b.pv[2] = *(const float4*)(Prow + 16);
    b.pv[3] = *(const float4*)(Prow + 20);
    b.ph[0] = phig[3 * bn + 0]; b.ph[1] = phig[3 * bn + 1]; b.ph[2] = phig[3 * bn + 2];
    b.pq[0] = piphig[3 * bn + 0]; b.pq[1] = piphig[3 * bn + 1]; b.pq[2] = piphig[3 * bn + 2];
}

__device__ __forceinline__ void computem(const InBuf& b, float* __restrict__ out,
                                         int bn, int fr, int h, int l)
{
    Frag8 FS, FSl, FP;
#pragma unroll
    for (int i = 0; i < 4; ++i) {
        const float4 s = b.sv[i];
        const float4 p = b.pv[i];
        const u32 ha = pk2(s.x, s.y);
        const u32 hb = pk2(s.z, s.w);
        FS.r[2*i]   = ha;
        FS.r[2*i+1] = hb;
        const float lx = s.x - asfloat(ha << 16);
        const float ly = s.y - asfloat(ha & 0xffff0000u);
        const float lz = s.z - asfloat(hb << 16);
        const float lw = s.w - asfloat(hb & 0xffff0000u);
        FSl.r[2*i]   = pk2(lx, ly);
        FSl.r[2*i+1] = pk2(lz, lw);
        FP.r[2*i]   = pk2(p.x, p.y);
        FP.r[2*i+1] = pk2(p.z, p.w);
    }

    // identity in D-layout: row (i&3)+8*(i>>2)+4h, col fr
    f32x16 If;
#pragma unroll
    for (int i = 0; i < 16; ++i)
        If[i] = (((i & 3) + 8 * (i >> 2) + 4 * h) == fr) ? 1.f : 0.f;

    // ---- U = S·P ; Ut = P·S (independent) ; H = U·U = S·P·S·P ----
    f32x16 U  = matmul(FS, FP, zero16());
    f32x16 Ut = matmul(FP, FS, zero16());
    Frag8 BU;  bconv(U,  BU);
    Frag8 BUt; bconv(Ut, BUt);              // as A-operand represents U
    f32x16 H = matmul(BUt, BU, zero16());

    // ---- M = 2DT·U − 2DT²·H ----
    f32x16 M;
#pragma unroll
    for (int i = 0; i < 16; ++i) M[i] = 0.02f * U[i] - 2e-4f * H[i];
    Frag8 FM; bconv(M, FM);                 // A-frag of M^T

    // ---- X = exp(M^T), Horner Taylor-3 ----
    f32x16 X = If;
#pragma unroll
    for (int d = 3; d >= 1; --d) {
        Frag8 BX; bconv_s(X, 1.f / (float)d, BX);
        X = matmul(FM, BX, If);
    }

    // ---- Yt = S·X ; Y = X^T·S = exp(M)·S  (hi/lo split, all in regs) ----
    Frag8 BE, BEl;
    bconv_split(X, BE, BEl);
    f32x16 Yt = matmul(FS,  BE,  zero16());
    Yt        = matmul(FSl, BE,  Yt);
    Yt        = matmul(FS,  BEl, Yt);
    f32x16 Y  = matmul(BE,  FS,  zero16()); // BE as A = exp(M); FS as B = S
    Y         = matmul(BEl, FS,  Y);
    Y         = matmul(BE,  FSl, Y);

    // ---- sym + eps·I in registers; direct coalesced stores ----
    const size_t obase = (size_t)bn * 1027;
    float* po = out + obase + (size_t)(4 * h) * 32 + fr;
#pragma unroll
    for (int i = 0; i < 16; ++i) {
        const int r = (i & 3) + 8 * (i >> 2) + 4 * h;
        float v = 0.5f * (Y[i] + Yt[i]);
        if (r == fr) v += 1e-8f;
        __builtin_nontemporal_store(v, po + (i & 3) * 32 + (i >> 2) * 256);
    }

    // ---- fused phi retraction (lane 0, double; floor-based mod 2pi) ----
    if (l == 0) {
        const double TWO_PI = 6.283185307179586476925287;
        const double PI_    = 3.141592653589793238462643;
        const double x = (double)b.ph[0] + 0.01 * (double)b.pq[0];
        const double y = (double)b.ph[1] + 0.01 * (double)b.pq[1];
        const double z = (double)b.ph[2] + 0.01 * (double)b.pq[2];
        const double theta = sqrt(x * x + y * y + z * z);
        const double ts = theta > 1e-12 ? theta : 1e-12;
        const double k2 = floor(theta * (1.0 / TWO_PI));
        const double tw = theta - k2 * TWO_PI;          // fmod(theta, 2pi), theta >= 0
        double t, sgn;
        if (tw > PI_) { t = TWO_PI - tw; sgn = -1.0; }
        else          { t = tw;          sgn = 1.0;  }
        const double rmax = PI_ - 0.01;
        if (t > rmax) t = rmax;
        const double f = sgn * t / ts;
        __builtin_nontemporal_store((float)(x * f), &out[obase + 1024]);
        __builtin_nontemporal_store((float)(y * f), &out[obase + 1025]);
        __builtin_nontemporal_store((float)(z * f), &out[obase + 1026]);
    }
}

__global__ __launch_bounds__(256)
void leapfrog_fused(const float* __restrict__ Sg, const float* __restrict__ Pg,
                    const float* __restrict__ phig, const float* __restrict__ piphig,
                    float* __restrict__ out, int total)
{
    const int w    = threadIdx.x >> 6;
    const int l    = threadIdx.x & 63;
    const int wave = blockIdx.x * 4 + w;
    const int nw   = gridDim.x * 4;        // total concurrent waves
    const int fr   = l & 31;
    const int h    = l >> 5;

    InBuf A, B;                             // named buffers, statically indexed

    int bn = wave;
    if (bn < total) loadm(Sg, Pg, phig, piphig, bn, fr, h, A);

#pragma unroll
    for (int i = 0; i < ITERS; i += 2) {
        const int bn1 = bn + nw;
        if (bn1 < total) loadm(Sg, Pg, phig, piphig, bn1, fr, h, B);   // prefetch
        if (bn  < total) computem(A, out, bn, fr, h, l);
        const int bn2 = bn1 + nw;
        if (bn2 < total) loadm(Sg, Pg, phig, piphig, bn2, fr, h, A);   // prefetch
        if (bn1 < total) computem(B, out, bn1, fr, h, l);
        bn = bn2;
    }
}

extern "C" void kernel_launch(void* const* d_in, const int* in_sizes, int n_in,
                              void* d_out, int out_size, void* d_ws, size_t ws_size,
                              hipStream_t stream)
{
    const float* Sg     = (const float*)d_in[0];
    const float* Pg     = (const float*)d_in[1];
    const float* phig   = (const float*)d_in[2];
    const float* piphig = (const float*)d_in[3];
    float* out = (float*)d_out;

    const int total  = in_sizes[0] / 1024;            // B*N = 32768 matrices
    const int blocks = (total + 4 * ITERS - 1) / (4 * ITERS);   // 2048

    leapfrog_fused<<<blocks, 256, 0, stream>>>(Sg, Pg, phig, piphig, out, total);
}

// Round 12
// 73.102 us; speedup vs baseline: 1.1062x; 1.1062x over previous
//
#include <hip/hip_runtime.h>
#include <hip/hip_bf16.h>
#include <math.h>

// Leapfrog on SPD(32), eigh-free, inverse-free, barrier-free, LDS-free.
//   U = S·P ; Ut = P·S (independent) ; H = U·U (= S·P·S·P = S·G)
//   M = 0.02·U - 2e-4·H  (= 2DT·S·pi_half)
//   E = exp(M^T) Taylor-3 (||M||<~0.17 -> trunc ~3e-5)
//   Yt = S·E ; Y = E^T·S = exp(M)·S   (two independent MFMA chains)
//   Sigma_new = 0.5(Y + Yt) + 1e-8 I  (sym in registers, direct stores)
// ONE wave per matrix (R6-proven; persistent/2-per-wave variants regressed
// or failed — R7/R8/R11). 32x32x16 bf16 MFMA; fragments straight from
// global; single-op v_perm_b32 TRUNC packs (R6-proven; RNE builtin costs
// extra VALU per R9); exact hi/lo splits absorb trunc error where it
// matters (S operands, final E). D-layout -> B-frag via
// v_permlane32_swap_b32 (verified: swap32(x,y) exchanges x.lanes[32:63]
// <-> y.lanes[0:31]); B-frag regs reused as A-operands and symmetric
// A-frags as B-operands (validated R10/R11). No setprio (R10: harmful in
// non-phase-split kernels). phi retraction fused (lane 0, double,
// floor-based mod-2pi), inputs prefetched with the matrix loads.

typedef unsigned int u32;
typedef __attribute__((ext_vector_type(8))) short bf16x8;
typedef __attribute__((ext_vector_type(16))) float f32x16;

union U4 { u32 u[4]; bf16x8 v; };

__device__ __forceinline__ bf16x8 mk8(u32 a, u32 b, u32 c, u32 d) {
    U4 t; t.u[0] = a; t.u[1] = b; t.u[2] = c; t.u[3] = d; return t.v;
}

// pack bf16(x),bf16(y) (TRUNCATED) into one u32: low16 = x, high16 = y
// (single v_perm_b32; R6-proven numerics with hi/lo splits downstream)
__device__ __forceinline__ u32 pkt(float x, float y) {
    return __builtin_amdgcn_perm(__float_as_uint(y), __float_as_uint(x), 0x07060302u);
}

__device__ __forceinline__ float asfloat(u32 b) {
    union { u32 u; float f; } c; c.u = b; return c.f;
}

__device__ __forceinline__ f32x16 zero16() {
    f32x16 z;
#pragma unroll
    for (int i = 0; i < 16; ++i) z[i] = 0.f;
    return z;
}

struct Frag8 { u32 r[8]; };

// v_permlane32_swap_b32: x.lanes[32:63] <-> y.lanes[0:31]
__device__ __forceinline__ void swap32(u32& x, u32& y) {
    asm("v_permlane32_swap_b32 %0, %1" : "+v"(x), "+v"(y));
}

// packed-pair regs p[8] (D-layout pairs) -> B-fragment order.
// swap32(x=p[lo], y=p[hi]):
//   x.lanes[32:63] <- old y.lanes[0:31]  = p[hi] of lane l-32   -> x == B.r[lo]
//   y.lanes[0:31]  <- old x.lanes[32:63] = p[lo] of lane l+32   -> y == B.r[hi]
__device__ __forceinline__ void xchg(const u32* p, Frag8& B) {
    { u32 x = p[0], y = p[2]; swap32(x, y); B.r[0] = x; B.r[2] = y; }
    { u32 x = p[1], y = p[3]; swap32(x, y); B.r[1] = x; B.r[3] = y; }
    { u32 x = p[4], y = p[6]; swap32(x, y); B.r[4] = x; B.r[6] = y; }
    { u32 x = p[5], y = p[7]; swap32(x, y); B.r[5] = x; B.r[7] = y; }
}

// D-layout f32x16 -> bf16 B-fragment, trunc pack (no scale)
__device__ __forceinline__ void bconv(const f32x16& X, Frag8& B) {
    u32 p[8];
#pragma unroll
    for (int i = 0; i < 8; ++i) p[i] = pkt(X[2*i], X[2*i+1]);
    xchg(p, B);
}

// D-layout f32x16 -> bf16 B-fragment, pre-scaled, trunc pack
__device__ __forceinline__ void bconv_s(const f32x16& X, float scale, Frag8& B) {
    u32 p[8];
#pragma unroll
    for (int i = 0; i < 8; ++i) p[i] = pkt(X[2*i] * scale, X[2*i+1] * scale);
    xchg(p, B);
}

// D-layout f32x16 -> exact hi/lo split bf16 B-fragments (hi trunc; lo =
// exact residual, trunc-packed -> residual-of-residual ~2^-16 rel)
__device__ __forceinline__ void bconv_split(const f32x16& X, Frag8& Bh, Frag8& Bl) {
    u32 p[8], q[8];
#pragma unroll
    for (int i = 0; i < 8; ++i) {
        const float x = X[2*i], y = X[2*i+1];
        p[i] = pkt(x, y);
        const float lx = x - asfloat(p[i] << 16);
        const float ly = y - asfloat(p[i] & 0xffff0000u);
        q[i] = pkt(lx, ly);
    }
    xchg(p, Bh);
    xchg(q, Bl);
}

__device__ __forceinline__ f32x16 MFMA1(const u32* a, const u32* b, f32x16 acc) {
    return __builtin_amdgcn_mfma_f32_32x32x16_bf16(
        mk8(a[0], a[1], a[2], a[3]), mk8(b[0], b[1], b[2], b[3]), acc, 0, 0, 0);
}

__device__ __forceinline__ f32x16 matmul(const Frag8& A, const Frag8& B, f32x16 acc) {
    acc = MFMA1(A.r,     B.r,     acc);   // k = 0..15
    acc = MFMA1(A.r + 4, B.r + 4, acc);   // k = 16..31
    return acc;
}

__global__ __launch_bounds__(256)
void leapfrog_fused(const float* __restrict__ Sg, const float* __restrict__ Pg,
                    const float* __restrict__ phig, const float* __restrict__ piphig,
                    float* __restrict__ out, int total)
{
    const int w  = threadIdx.x >> 6;
    const int l  = threadIdx.x & 63;
    const int bn = blockIdx.x * 4 + w;
    if (bn >= total) return;            // wave-uniform; no barriers, no LDS

    const int fr = l & 31;
    const int h  = l >> 5;
    const size_t gbase = (size_t)bn * 1024;

    // ---- fragment loads straight from global; phi prefetched alongside ----
    const float* Srow = Sg + gbase + fr * 32 + h * 8;
    const float* Prow = Pg + gbase + fr * 32 + h * 8;
    const float4 sv[4] = { *(const float4*)(Srow +  0), *(const float4*)(Srow +  4),
                           *(const float4*)(Srow + 16), *(const float4*)(Srow + 20) };
    const float4 pv[4] = { *(const float4*)(Prow +  0), *(const float4*)(Prow +  4),
                           *(const float4*)(Prow + 16), *(const float4*)(Prow + 20) };
    const float phx = phig[3 * bn + 0], phy = phig[3 * bn + 1], phz = phig[3 * bn + 2];
    const float qhx = piphig[3 * bn + 0], qhy = piphig[3 * bn + 1], qhz = piphig[3 * bn + 2];

    Frag8 FS, FSl, FP;
#pragma unroll
    for (int i = 0; i < 4; ++i) {
        const float4 s = sv[i];
        const float4 p = pv[i];
        const u32 ha = pkt(s.x, s.y);
        const u32 hb = pkt(s.z, s.w);
        FS.r[2*i]   = ha;
        FS.r[2*i+1] = hb;
        const float lx = s.x - asfloat(ha << 16);
        const float ly = s.y - asfloat(ha & 0xffff0000u);
        const float lz = s.z - asfloat(hb << 16);
        const float lw = s.w - asfloat(hb & 0xffff0000u);
        FSl.r[2*i]   = pkt(lx, ly);
        FSl.r[2*i+1] = pkt(lz, lw);
        FP.r[2*i]   = pkt(p.x, p.y);
        FP.r[2*i+1] = pkt(p.z, p.w);
    }

    // identity in D-layout: row (i&3)+8*(i>>2)+4h, col fr
    f32x16 If;
#pragma unroll
    for (int i = 0; i < 16; ++i)
        If[i] = (((i & 3) + 8 * (i >> 2) + 4 * h) == fr) ? 1.f : 0.f;

    // ---- U = S·P ; Ut = P·S (independent chains) ; H = U·U = S·P·S·P ----
    // (S, P symmetric -> A-frags serve as B-operands and vice versa.)
    f32x16 U  = matmul(FS, FP, zero16());
    f32x16 Ut = matmul(FP, FS, zero16());
    Frag8 BU;  bconv(U,  BU);
    Frag8 BUt; bconv(Ut, BUt);              // as A-operand represents U
    f32x16 H = matmul(BUt, BU, zero16());

    // ---- M = 2DT·U − 2DT²·H ----
    f32x16 M;
#pragma unroll
    for (int i = 0; i < 16; ++i) M[i] = 0.02f * U[i] - 2e-4f * H[i];
    Frag8 FM; bconv(M, FM);                 // A-frag of M^T

    // ---- X = exp(M^T), Horner Taylor-3: X = I + (1/d)·M^T·X, d=3..1 ----
    f32x16 X = If;
#pragma unroll
    for (int d = 3; d >= 1; --d) {
        Frag8 BX; bconv_s(X, 1.f / (float)d, BX);
        X = matmul(FM, BX, If);
    }

    // ---- Yt = S·X ; Y = X^T·S = exp(M)·S  (independent chains, hi/lo) ----
    Frag8 BE, BEl;
    bconv_split(X, BE, BEl);
    f32x16 Yt = matmul(FS,  BE,  zero16());
    f32x16 Y  = matmul(BE,  FS,  zero16()); // BE as A = exp(M); FS as B = S
    Yt        = matmul(FSl, BE,  Yt);
    Y         = matmul(BEl, FS,  Y);
    Yt        = matmul(FS,  BEl, Yt);
    Y         = matmul(BE,  FSl, Y);

    // ---- sym + eps·I in registers; direct coalesced stores ----
    const size_t obase = (size_t)bn * 1027;
    float* po = out + obase + (size_t)(4 * h) * 32 + fr;
#pragma unroll
    for (int i = 0; i < 16; ++i) {
        const int r = (i & 3) + 8 * (i >> 2) + 4 * h;
        float v = 0.5f * (Y[i] + Yt[i]);
        if (r == fr) v += 1e-8f;
        __builtin_nontemporal_store(v, po + (i & 3) * 32 + (i >> 2) * 256);
    }

    // ---- fused phi retraction (lane 0, double; floor-based mod 2pi) ----
    if (l == 0) {
        const double TWO_PI = 6.283185307179586476925287;
        const double PI_    = 3.141592653589793238462643;
        const double x = (double)phx + 0.01 * (double)qhx;
        const double y = (double)phy + 0.01 * (double)qhy;
        const double z = (double)phz + 0.01 * (double)qhz;
        const double theta = sqrt(x * x + y * y + z * z);
        const double ts = theta > 1e-12 ? theta : 1e-12;
        const double k2 = floor(theta * (1.0 / TWO_PI));
        const double tw = theta - k2 * TWO_PI;          // fmod(theta, 2pi), theta >= 0
        double t, sgn;
        if (tw > PI_) { t = TWO_PI - tw; sgn = -1.0; }
        else          { t = tw;          sgn = 1.0;  }
        const double rmax = PI_ - 0.01;
        if (t > rmax) t = rmax;
        const double f = sgn * t / ts;
        __builtin_nontemporal_store((float)(x * f), &out[obase + 1024]);
        __builtin_nontemporal_store((float)(y * f), &out[obase + 1025]);
        __builtin_nontemporal_store((float)(z * f), &out[obase + 1026]);
    }
}

extern "C" void kernel_launch(void* const* d_in, const int* in_sizes, int n_in,
                              void* d_out, int out_size, void* d_ws, size_t ws_size,
                              hipStream_t stream)
{
    const float* Sg     = (const float*)d_in[0];
    const float* Pg     = (const float*)d_in[1];
    const float* phig   = (const float*)d_in[2];
    const float* piphig = (const float*)d_in[3];
    float* out = (float*)d_out;

    const int total = in_sizes[0] / 1024;   // B*N = 32768 matrices

    leapfrog_fused<<<(total + 3) / 4, 256, 0, stream>>>(Sg, Pg, phig, piphig, out, total);
}

// Round 13
// 69.201 us; speedup vs baseline: 1.1686x; 1.0564x over previous
//
#include <hip/hip_runtime.h>
#include <hip/hip_bf16.h>
#include <math.h>

// Leapfrog on SPD(32), eigh-free, inverse-free, barrier-free MFMA version.
//   U = S·P ; Ut = P·S (independent) ; H = U·U (= S·P·S·P = S·G)
//   M = 0.02·U - 2e-4·H  (= 2DT·S·pi_half)
//   E = exp(M^T) Taylor-3 ; Sigma_new = sym(S·E) + 1e-8 I
// ONE wave per matrix, R6-proven skeleton: trunc v_perm packs, LDS-bounce
// sym epilogue (contiguous 256B stores -> minimal write traffic; R12's
// scattered reg-epilogue cost +26MB writes), no setprio (R10), VGPR<=64.
// Chain cuts validated in R10/R12: U^2-head (parallel U/Ut) and Taylor-3.
// D-layout -> B-frag via v_permlane32_swap_b32 (verified: swap32(x,y)
// exchanges x.lanes[32:63] <-> y.lanes[0:31]); B-frags reused as
// A-operands (H=U·U), symmetric A-frags as B-operands. Final S·E in exact
// hi/lo split bf16. phi retraction fused (lane 0, double, floor-mod-2pi),
// phi inputs prefetched with the matrix loads.

typedef unsigned int u32;
typedef __attribute__((ext_vector_type(8))) short bf16x8;
typedef __attribute__((ext_vector_type(16))) float f32x16;

#define FPAD 33   // f32 row stride of sym buffer: 33 mod 32 == 1 -> conflict-free

union U4 { u32 u[4]; bf16x8 v; };

__device__ __forceinline__ bf16x8 mk8(u32 a, u32 b, u32 c, u32 d) {
    U4 t; t.u[0] = a; t.u[1] = b; t.u[2] = c; t.u[3] = d; return t.v;
}

// pack bf16(x),bf16(y) (truncated) into one u32: low16 = x, high16 = y
__device__ __forceinline__ u32 pkt(float x, float y) {
    return __builtin_amdgcn_perm(__float_as_uint(y), __float_as_uint(x), 0x07060302u);
}

__device__ __forceinline__ float asfloat(u32 b) {
    union { u32 u; float f; } c; c.u = b; return c.f;
}

__device__ __forceinline__ f32x16 zero16() {
    f32x16 z;
#pragma unroll
    for (int i = 0; i < 16; ++i) z[i] = 0.f;
    return z;
}

struct Frag8 { u32 r[8]; };

// v_permlane32_swap_b32: x.lanes[32:63] <-> y.lanes[0:31]
__device__ __forceinline__ void swap32(u32& x, u32& y) {
    asm("v_permlane32_swap_b32 %0, %1" : "+v"(x), "+v"(y));
}

// packed-pair regs p[8] (D-layout pairs) -> B-fragment order.
// swap32(x=p[lo], y=p[hi]):
//   x.lanes[32:63] <- old y.lanes[0:31]  = p[hi] of lane l-32   -> x == B.r[lo]
//   y.lanes[0:31]  <- old x.lanes[32:63] = p[lo] of lane l+32   -> y == B.r[hi]
__device__ __forceinline__ void xchg(const u32* p, Frag8& B) {
    { u32 x = p[0], y = p[2]; swap32(x, y); B.r[0] = x; B.r[2] = y; }
    { u32 x = p[1], y = p[3]; swap32(x, y); B.r[1] = x; B.r[3] = y; }
    { u32 x = p[4], y = p[6]; swap32(x, y); B.r[4] = x; B.r[6] = y; }
    { u32 x = p[5], y = p[7]; swap32(x, y); B.r[5] = x; B.r[7] = y; }
}

// D-layout f32x16 -> bf16 B-fragment, trunc pack (no scale)
__device__ __forceinline__ void bconv(const f32x16& X, Frag8& B) {
    u32 p[8];
#pragma unroll
    for (int i = 0; i < 8; ++i) p[i] = pkt(X[2*i], X[2*i+1]);
    xchg(p, B);
}

// D-layout f32x16 -> bf16 B-fragment, pre-scaled, trunc pack
__device__ __forceinline__ void bconv_s(const f32x16& X, float scale, Frag8& B) {
    u32 p[8];
#pragma unroll
    for (int i = 0; i < 8; ++i) p[i] = pkt(X[2*i] * scale, X[2*i+1] * scale);
    xchg(p, B);
}

// D-layout f32x16 -> exact hi/lo split bf16 B-fragments
__device__ __forceinline__ void bconv_split(const f32x16& X, Frag8& Bh, Frag8& Bl) {
    u32 p[8], q[8];
#pragma unroll
    for (int i = 0; i < 8; ++i) {
        const float x = X[2*i], y = X[2*i+1];
        p[i] = pkt(x, y);
        const float lx = x - asfloat(p[i] << 16);
        const float ly = y - asfloat(p[i] & 0xffff0000u);
        q[i] = pkt(lx, ly);
    }
    xchg(p, Bh);
    xchg(q, Bl);
}

__device__ __forceinline__ f32x16 MFMA1(const u32* a, const u32* b, f32x16 acc) {
    return __builtin_amdgcn_mfma_f32_32x32x16_bf16(
        mk8(a[0], a[1], a[2], a[3]), mk8(b[0], b[1], b[2], b[3]), acc, 0, 0, 0);
}

__device__ __forceinline__ f32x16 matmul(const Frag8& A, const Frag8& B, f32x16 acc) {
    acc = MFMA1(A.r,     B.r,     acc);   // k = 0..15
    acc = MFMA1(A.r + 4, B.r + 4, acc);   // k = 16..31
    return acc;
}

__global__ __launch_bounds__(256)
void leapfrog_fused(const float* __restrict__ Sg, const float* __restrict__ Pg,
                    const float* __restrict__ phig, const float* __restrict__ piphig,
                    float* __restrict__ out, int total)
{
    __shared__ __align__(16) float symb[4 * 32 * FPAD];

    const int w  = threadIdx.x >> 6;
    const int l  = threadIdx.x & 63;
    const int bn = blockIdx.x * 4 + w;
    if (bn >= total) return;            // wave-uniform; kernel has no barriers

    float* sy = symb + w * 32 * FPAD;

    const int fr = l & 31;
    const int h  = l >> 5;
    const size_t gbase = (size_t)bn * 1024;

    // ---- fragment loads straight from global; phi prefetched alongside ----
    const float* Srow = Sg + gbase + fr * 32 + h * 8;
    const float* Prow = Pg + gbase + fr * 32 + h * 8;
    const float4 sv[4] = { *(const float4*)(Srow +  0), *(const float4*)(Srow +  4),
                           *(const float4*)(Srow + 16), *(const float4*)(Srow + 20) };
    const float4 pv[4] = { *(const float4*)(Prow +  0), *(const float4*)(Prow +  4),
                           *(const float4*)(Prow + 16), *(const float4*)(Prow + 20) };
    const float phx = phig[3 * bn + 0], phy = phig[3 * bn + 1], phz = phig[3 * bn + 2];
    const float qhx = piphig[3 * bn + 0], qhy = piphig[3 * bn + 1], qhz = piphig[3 * bn + 2];

    Frag8 FS, FSl, FP;
#pragma unroll
    for (int i = 0; i < 4; ++i) {
        const float4 s = sv[i];
        const float4 p = pv[i];
        const u32 ha = pkt(s.x, s.y);
        const u32 hb = pkt(s.z, s.w);
        FS.r[2*i]   = ha;
        FS.r[2*i+1] = hb;
        const float lx = s.x - asfloat(ha << 16);
        const float ly = s.y - asfloat(ha & 0xffff0000u);
        const float lz = s.z - asfloat(hb << 16);
        const float lw = s.w - asfloat(hb & 0xffff0000u);
        FSl.r[2*i]   = pkt(lx, ly);
        FSl.r[2*i+1] = pkt(lz, lw);
        FP.r[2*i]   = pkt(p.x, p.y);
        FP.r[2*i+1] = pkt(p.z, p.w);
    }

    // identity in D-layout: row (i&3)+8*(i>>2)+4h, col fr
    f32x16 If;
#pragma unroll
    for (int i = 0; i < 16; ++i)
        If[i] = (((i & 3) + 8 * (i >> 2) + 4 * h) == fr) ? 1.f : 0.f;

    // ---- U = S·P ; Ut = P·S (independent chains) ; H = U·U = S·P·S·P ----
    f32x16 U  = matmul(FS, FP, zero16());
    f32x16 Ut = matmul(FP, FS, zero16());
    Frag8 BU;  bconv(U,  BU);
    Frag8 BUt; bconv(Ut, BUt);              // as A-operand represents U
    f32x16 H = matmul(BUt, BU, zero16());

    // ---- M = 2DT·U − 2DT²·H ----
    f32x16 M;
#pragma unroll
    for (int i = 0; i < 16; ++i) M[i] = 0.02f * U[i] - 2e-4f * H[i];
    Frag8 FM; bconv(M, FM);                 // A-frag of M^T

    // ---- X = exp(M^T), Horner Taylor-3: X = I + (1/d)·M^T·X, d=3..1 ----
    f32x16 X = If;
#pragma unroll
    for (int d = 3; d >= 1; --d) {
        Frag8 BX; bconv_s(X, 1.f / (float)d, BX);
        X = matmul(FM, BX, If);
    }

    // ---- Y^T = S·X, hi/lo split (Shi·Xhi ; Slo·Xhi + Shi·Xlo) ----
    Frag8 BE, BEl;
    bconv_split(X, BE, BEl);
    f32x16 Y1 = matmul(FS, BE, zero16());
    f32x16 Y2 = matmul(FSl, BE, zero16());
    Y2 = matmul(FS, BEl, Y2);

    // ---- sym + eps·I via conflict-free LDS bounce (intra-wave ordering) ----
#pragma unroll
    for (int i = 0; i < 16; ++i) {
        const int r = (i & 3) + 8 * (i >> 2) + 4 * h;
        sy[r * FPAD + fr] = Y1[i] + Y2[i];
    }
    const size_t obase = (size_t)bn * 1027;
#pragma unroll
    for (int k = 0; k < 16; ++k) {
        const int idx = k * 64 + l;
        const int r = idx >> 5, c = idx & 31;
        const float a = sy[r * FPAD + c];
        const float b = sy[c * FPAD + r];
        float v = 0.5f * (a + b);
        if (r == c) v += 1e-8f;
        __builtin_nontemporal_store(v, &out[obase + idx]);
    }

    // ---- fused phi retraction (lane 0, double; floor-based mod 2pi) ----
    if (l == 0) {
        const double TWO_PI = 6.283185307179586476925287;
        const double PI_    = 3.141592653589793238462643;
        const double x = (double)phx + 0.01 * (double)qhx;
        const double y = (double)phy + 0.01 * (double)qhy;
        const double z = (double)phz + 0.01 * (double)qhz;
        const double theta = sqrt(x * x + y * y + z * z);
        const double ts = theta > 1e-12 ? theta : 1e-12;
        const double k2 = floor(theta * (1.0 / TWO_PI));
        const double tw = theta - k2 * TWO_PI;          // fmod(theta, 2pi), theta >= 0
        double t, sgn;
        if (tw > PI_) { t = TWO_PI - tw; sgn = -1.0; }
        else          { t = tw;          sgn = 1.0;  }
        const double rmax = PI_ - 0.01;
        if (t > rmax) t = rmax;
        const double f = sgn * t / ts;
        __builtin_nontemporal_store((float)(x * f), &out[obase + 1024]);
        __builtin_nontemporal_store((float)(y * f), &out[obase + 1025]);
        __builtin_nontemporal_store((float)(z * f), &out[obase + 1026]);
    }
}

extern "C" void kernel_launch(void* const* d_in, const int* in_sizes, int n_in,
                              void* d_out, int out_size, void* d_ws, size_t ws_size,
                              hipStream_t stream)
{
    const float* Sg     = (const float*)d_in[0];
    const float* Pg     = (const float*)d_in[1];
    const float* phig   = (const float*)d_in[2];
    const float* piphig = (const float*)d_in[3];
    float* out = (float*)d_out;

    const int total = in_sizes[0] / 1024;   // B*N = 32768 matrices

    leapfrog_fused<<<(total + 3) / 4, 256, 0, stream>>>(Sg, Pg, phig, piphig, out, total);
}

// Round 14
// 68.772 us; speedup vs baseline: 1.1759x; 1.0062x over previous
//
#include <hip/hip_runtime.h>
#include <hip/hip_bf16.h>
#include <math.h>

// Leapfrog on SPD(32), eigh-free, inverse-free, barrier-free MFMA version.
//   U = S·P ; Ut = P·S (independent) ; H = U·U (= S·P·S·P = S·G)
//   M = 0.02·U - 2e-4·H  (= 2DT·S·pi_half)
//   E = exp(M^T) Taylor-3, first stage in f32 VALU: X3 = I + M/3 (free),
//   then X2 = I + (1/2)M^T·X3, X1 = I + M^T·X2 (2 MFMA stages only)
//   Sigma_new = sym(S·E) + 1e-8 I
// ONE wave per matrix, R6/R13 skeleton: trunc v_perm packs, LDS-bounce sym
// epilogue (contiguous stores; scattered reg-epilogue costs +26MB writes,
// R12), regular (cached) loads — L3 serves ~half of input re-reads
// (FETCH 132MB < 268MB input), so NO nt hint on loads; nt on stores only.
// Tail: three INDEPENDENT 2-MFMA chains (FS·BE ∥ FSl·BE ∥ FS·BEl) summed
// in VALU. D-layout -> B-frag via v_permlane32_swap_b32 (verified:
// swap32(x,y) exchanges x.lanes[32:63] <-> y.lanes[0:31]); B-frags reused
// as A-operands (H=U·U). phi retraction fused (lanes 0-2, double).

typedef unsigned int u32;
typedef __attribute__((ext_vector_type(8))) short bf16x8;
typedef __attribute__((ext_vector_type(16))) float f32x16;

#define FPAD 33   // f32 row stride of sym buffer: 33 mod 32 == 1 -> conflict-free

union U4 { u32 u[4]; bf16x8 v; };

__device__ __forceinline__ bf16x8 mk8(u32 a, u32 b, u32 c, u32 d) {
    U4 t; t.u[0] = a; t.u[1] = b; t.u[2] = c; t.u[3] = d; return t.v;
}

// pack bf16(x),bf16(y) (truncated) into one u32: low16 = x, high16 = y
__device__ __forceinline__ u32 pkt(float x, float y) {
    return __builtin_amdgcn_perm(__float_as_uint(y), __float_as_uint(x), 0x07060302u);
}

__device__ __forceinline__ float asfloat(u32 b) {
    union { u32 u; float f; } c; c.u = b; return c.f;
}

__device__ __forceinline__ f32x16 zero16() {
    f32x16 z;
#pragma unroll
    for (int i = 0; i < 16; ++i) z[i] = 0.f;
    return z;
}

struct Frag8 { u32 r[8]; };

// v_permlane32_swap_b32: x.lanes[32:63] <-> y.lanes[0:31]
__device__ __forceinline__ void swap32(u32& x, u32& y) {
    asm("v_permlane32_swap_b32 %0, %1" : "+v"(x), "+v"(y));
}

// packed-pair regs p[8] (D-layout pairs) -> B-fragment order.
// swap32(x=p[lo], y=p[hi]):
//   x.lanes[32:63] <- old y.lanes[0:31]  = p[hi] of lane l-32   -> x == B.r[lo]
//   y.lanes[0:31]  <- old x.lanes[32:63] = p[lo] of lane l+32   -> y == B.r[hi]
__device__ __forceinline__ void xchg(const u32* p, Frag8& B) {
    { u32 x = p[0], y = p[2]; swap32(x, y); B.r[0] = x; B.r[2] = y; }
    { u32 x = p[1], y = p[3]; swap32(x, y); B.r[1] = x; B.r[3] = y; }
    { u32 x = p[4], y = p[6]; swap32(x, y); B.r[4] = x; B.r[6] = y; }
    { u32 x = p[5], y = p[7]; swap32(x, y); B.r[5] = x; B.r[7] = y; }
}

// D-layout f32x16 -> bf16 B-fragment, trunc pack (no scale)
__device__ __forceinline__ void bconv(const f32x16& X, Frag8& B) {
    u32 p[8];
#pragma unroll
    for (int i = 0; i < 8; ++i) p[i] = pkt(X[2*i], X[2*i+1]);
    xchg(p, B);
}

// D-layout f32x16 -> bf16 B-fragment, pre-scaled, trunc pack
__device__ __forceinline__ void bconv_s(const f32x16& X, float scale, Frag8& B) {
    u32 p[8];
#pragma unroll
    for (int i = 0; i < 8; ++i) p[i] = pkt(X[2*i] * scale, X[2*i+1] * scale);
    xchg(p, B);
}

// D-layout f32x16 -> exact hi/lo split bf16 B-fragments
__device__ __forceinline__ void bconv_split(const f32x16& X, Frag8& Bh, Frag8& Bl) {
    u32 p[8], q[8];
#pragma unroll
    for (int i = 0; i < 8; ++i) {
        const float x = X[2*i], y = X[2*i+1];
        p[i] = pkt(x, y);
        const float lx = x - asfloat(p[i] << 16);
        const float ly = y - asfloat(p[i] & 0xffff0000u);
        q[i] = pkt(lx, ly);
    }
    xchg(p, Bh);
    xchg(q, Bl);
}

__device__ __forceinline__ f32x16 MFMA1(const u32* a, const u32* b, f32x16 acc) {
    return __builtin_amdgcn_mfma_f32_32x32x16_bf16(
        mk8(a[0], a[1], a[2], a[3]), mk8(b[0], b[1], b[2], b[3]), acc, 0, 0, 0);
}

__device__ __forceinline__ f32x16 matmul(const Frag8& A, const Frag8& B, f32x16 acc) {
    acc = MFMA1(A.r,     B.r,     acc);   // k = 0..15
    acc = MFMA1(A.r + 4, B.r + 4, acc);   // k = 16..31
    return acc;
}

__global__ __launch_bounds__(256)
void leapfrog_fused(const float* __restrict__ Sg, const float* __restrict__ Pg,
                    const float* __restrict__ phig, const float* __restrict__ piphig,
                    float* __restrict__ out, int total)
{
    __shared__ __align__(16) float symb[4 * 32 * FPAD];

    const int w  = threadIdx.x >> 6;
    const int l  = threadIdx.x & 63;
    const int bn = blockIdx.x * 4 + w;
    if (bn >= total) return;            // wave-uniform; kernel has no barriers

    float* sy = symb + w * 32 * FPAD;

    const int fr = l & 31;
    const int h  = l >> 5;
    const size_t gbase = (size_t)bn * 1024;

    // ---- fragment loads straight from global; phi prefetched alongside ----
    const float* Srow = Sg + gbase + fr * 32 + h * 8;
    const float* Prow = Pg + gbase + fr * 32 + h * 8;
    const float4 sv[4] = { *(const float4*)(Srow +  0), *(const float4*)(Srow +  4),
                           *(const float4*)(Srow + 16), *(const float4*)(Srow + 20) };
    const float4 pv[4] = { *(const float4*)(Prow +  0), *(const float4*)(Prow +  4),
                           *(const float4*)(Prow + 16), *(const float4*)(Prow + 20) };
    // phi inputs: lanes 0-2 each handle one component in the epilogue
    float phc = 0.f, qhc = 0.f;
    if (l < 3) { phc = phig[3 * bn + l]; qhc = piphig[3 * bn + l]; }

    Frag8 FS, FSl, FP;
#pragma unroll
    for (int i = 0; i < 4; ++i) {
        const float4 s = sv[i];
        const float4 p = pv[i];
        const u32 ha = pkt(s.x, s.y);
        const u32 hb = pkt(s.z, s.w);
        FS.r[2*i]   = ha;
        FS.r[2*i+1] = hb;
        const float lx = s.x - asfloat(ha << 16);
        const float ly = s.y - asfloat(ha & 0xffff0000u);
        const float lz = s.z - asfloat(hb << 16);
        const float lw = s.w - asfloat(hb & 0xffff0000u);
        FSl.r[2*i]   = pkt(lx, ly);
        FSl.r[2*i+1] = pkt(lz, lw);
        FP.r[2*i]   = pkt(p.x, p.y);
        FP.r[2*i+1] = pkt(p.z, p.w);
    }

    // identity in D-layout: row (i&3)+8*(i>>2)+4h, col fr
    f32x16 If;
#pragma unroll
    for (int i = 0; i < 16; ++i)
        If[i] = (((i & 3) + 8 * (i >> 2) + 4 * h) == fr) ? 1.f : 0.f;

    // ---- U = S·P ; Ut = P·S (independent chains) ; H = U·U = S·P·S·P ----
    f32x16 U  = matmul(FS, FP, zero16());
    f32x16 Ut = matmul(FP, FS, zero16());
    Frag8 BU;  bconv(U,  BU);
    Frag8 BUt; bconv(Ut, BUt);              // as A-operand represents U
    f32x16 H = matmul(BUt, BU, zero16());

    // ---- M = 2DT·U − 2DT²·H ;  X3 = I + M/3 (f32 VALU — free stage) ----
    f32x16 M, X;
#pragma unroll
    for (int i = 0; i < 16; ++i) {
        M[i] = 0.02f * U[i] - 2e-4f * H[i];
        X[i] = If[i] + (1.0f / 3.0f) * M[i];
    }
    Frag8 FM; bconv(M, FM);                 // A-frag of M^T

    // ---- X2 = I + (1/2)·M^T·X3 ; X1 = I + M^T·X2 (2 MFMA stages) ----
    {
        Frag8 BX; bconv_s(X, 0.5f, BX);
        X = matmul(FM, BX, If);
    }
    {
        Frag8 BX; bconv(X, BX);
        X = matmul(FM, BX, If);
    }

    // ---- Y^T = S·X, hi/lo split, three INDEPENDENT 2-MFMA chains ----
    Frag8 BE, BEl;
    bconv_split(X, BE, BEl);
    f32x16 Y1 = matmul(FS,  BE,  zero16());
    f32x16 Y2 = matmul(FSl, BE,  zero16());
    f32x16 Y3 = matmul(FS,  BEl, zero16());

    // ---- sym + eps·I via conflict-free LDS bounce (intra-wave ordering) ----
#pragma unroll
    for (int i = 0; i < 16; ++i) {
        const int r = (i & 3) + 8 * (i >> 2) + 4 * h;
        sy[r * FPAD + fr] = Y1[i] + Y2[i] + Y3[i];
    }
    const size_t obase = (size_t)bn * 1027;
#pragma unroll
    for (int k = 0; k < 16; ++k) {
        const int idx = k * 64 + l;
        const int r = idx >> 5, c = idx & 31;
        const float a = sy[r * FPAD + c];
        const float b = sy[c * FPAD + r];
        float v = 0.5f * (a + b);
        if (r == c) v += 1e-8f;
        __builtin_nontemporal_store(v, &out[obase + idx]);
    }

    // ---- fused phi retraction (lanes 0-2, double; floor-based mod 2pi) ----
    if (l < 3) {
        const double TWO_PI = 6.283185307179586476925287;
        const double PI_    = 3.141592653589793238462643;
        // each of lanes 0..2 computes the same theta from broadcast sums:
        // reconstruct all three components via readlane-free shuffles
        const double c0 = (double)__shfl(phc, 0, 64) + 0.01 * (double)__shfl(qhc, 0, 64);
        const double c1 = (double)__shfl(phc, 1, 64) + 0.01 * (double)__shfl(qhc, 1, 64);
        const double c2 = (double)__shfl(phc, 2, 64) + 0.01 * (double)__shfl(qhc, 2, 64);
        const double me = (l == 0) ? c0 : (l == 1) ? c1 : c2;
        const double theta = sqrt(c0 * c0 + c1 * c1 + c2 * c2);
        const double ts = theta > 1e-12 ? theta : 1e-12;
        const double k2 = floor(theta * (1.0 / TWO_PI));
        const double tw = theta - k2 * TWO_PI;          // fmod(theta, 2pi), theta >= 0
        double t, sgn;
        if (tw > PI_) { t = TWO_PI - tw; sgn = -1.0; }
        else          { t = tw;          sgn = 1.0;  }
        const double rmax = PI_ - 0.01;
        if (t > rmax) t = rmax;
        const double f = sgn * t / ts;
        __builtin_nontemporal_store((float)(me * f), &out[obase + 1024 + l]);
    }
}

extern "C" void kernel_launch(void* const* d_in, const int* in_sizes, int n_in,
                              void* d_out, int out_size, void* d_ws, size_t ws_size,
                              hipStream_t stream)
{
    const float* Sg     = (const float*)d_in[0];
    const float* Pg     = (const float*)d_in[1];
    const float* phig   = (const float*)d_in[2];
    const float* piphig = (const float*)d_in[3];
    float* out = (float*)d_out;

    const int total = in_sizes[0] / 1024;   // B*N = 32768 matrices

    leapfrog_fused<<<(total + 3) / 4, 256, 0, stream>>>(Sg, Pg, phig, piphig, out, total);
}